// Round 1
// baseline (361.293 us; speedup 1.0000x reference)
//
#include <hip/hip_runtime.h>
#include <hip/hip_bf16.h>

#define BATCH 8
#define CTX   2048
#define EMB   1024
#define HD    128

using bf16x8 = __attribute__((ext_vector_type(8))) short;
using fx4    = __attribute__((ext_vector_type(4))) float;

__device__ __forceinline__ ushort f2bf(float f) {
    union { float f; unsigned u; } v; v.f = f;
    unsigned u = v.u;
    u += 0x7fffu + ((u >> 16) & 1u);   // RNE
    return (ushort)(u >> 16);
}

// ---------------- kernel 1: W (E,H) fp32 -> Wt (3,H,E) bf16 ----------------
__global__ void wt_kernel(const float* __restrict__ Wq, const float* __restrict__ Wk,
                          const float* __restrict__ Wv, ushort* __restrict__ Wt) {
    int idx = blockIdx.x * blockDim.x + threadIdx.x;      // [3][HD][EMB]
    int e = idx % EMB;
    int h = (idx / EMB) % HD;
    int w = idx / (EMB * HD);
    const float* W = (w == 0) ? Wq : (w == 1) ? Wk : Wv;
    Wt[idx] = f2bf(W[e * HD + h]);
}

// ---------------- kernel 2: fused q/k/v projection --------------------------
// grid = M/64 blocks (M = B*C = 16384), 256 thr (4 waves), each wave 16 rows.
// q stored bf16 [B*C][H] pre-scaled by 1/sqrt(E); k bf16 [B*C][H];
// v stored TRANSPOSED bf16 [B][H][C].
__global__ __launch_bounds__(256) void proj_kernel(
        const float* __restrict__ x, const ushort* __restrict__ Wt,
        ushort* __restrict__ q, ushort* __restrict__ k, ushort* __restrict__ vt) {
    const int wave = threadIdx.x >> 6;
    const int lane = threadIdx.x & 63;
    const int lo = lane & 15, hi = lane >> 4;
    const int arow = blockIdx.x * 64 + wave * 16 + lo;    // A-fragment row

    fx4 acc[3][8];
#pragma unroll
    for (int m = 0; m < 3; m++)
#pragma unroll
        for (int n = 0; n < 8; n++) acc[m][n] = fx4{0.f, 0.f, 0.f, 0.f};

    for (int k0 = 0; k0 < EMB; k0 += 32) {
        // A fragment: 8 contiguous fp32 -> bf16
        const float* xp = x + (size_t)arow * EMB + k0 + hi * 8;
        fx4 a0 = *(const fx4*)(xp);
        fx4 a1 = *(const fx4*)(xp + 4);
        bf16x8 af;
#pragma unroll
        for (int j = 0; j < 4; j++) {
            af[j]     = (short)f2bf(a0[j]);
            af[j + 4] = (short)f2bf(a1[j]);
        }
#pragma unroll
        for (int m = 0; m < 3; m++) {
            const ushort* wb = Wt + (size_t)m * (HD * EMB) + k0 + hi * 8;
#pragma unroll
            for (int n = 0; n < 8; n++) {
                bf16x8 bf = *(const bf16x8*)(wb + (n * 16 + lo) * EMB);
                acc[m][n] = __builtin_amdgcn_mfma_f32_16x16x32_bf16(af, bf, acc[m][n], 0, 0, 0);
            }
        }
    }

    // Epilogue: D layout col = lane&15, row = (lane>>4)*4 + j
    const int orow = blockIdx.x * 64 + wave * 16 + hi * 4;
    const float qscale = 0.03125f;   // 1/sqrt(1024)
#pragma unroll
    for (int n = 0; n < 8; n++) {
        const int c = n * 16 + lo;
#pragma unroll
        for (int j = 0; j < 4; j++) {
            const int r = orow + j;
            q[r * HD + c] = f2bf(acc[0][n][j] * qscale);
            k[r * HD + c] = f2bf(acc[1][n][j]);
            const int b = r >> 11, cc = r & (CTX - 1);
            vt[((b * HD) + c) * CTX + cc] = f2bf(acc[2][n][j]);
        }
    }
}

// ---------------- kernel 3: causal flash attention --------------------------
// grid = (C/32, B), 128 thr (2 waves), each wave owns 16 q-rows.
// K/Vt fragments loaded directly from global (L2-resident per batch).
__global__ __launch_bounds__(128) void attn_kernel(
        const ushort* __restrict__ q, const ushort* __restrict__ k,
        const ushort* __restrict__ vt, float* __restrict__ out) {
    __shared__ ushort p_lds[2][16][64];

    const int b    = blockIdx.y;
    const int qt   = gridDim.x - 1 - blockIdx.x;   // longest tiles dispatched first
    const int wave = threadIdx.x >> 6;
    const int lane = threadIdx.x & 63;
    const int lo = lane & 15, hi = lane >> 4;
    const int q0 = qt * 32 + wave * 16;            // wave's first q-row (within batch)

    const ushort* qb = q  + (size_t)b * CTX * HD;
    const ushort* kb = k  + (size_t)b * CTX * HD;
    const ushort* vb = vt + (size_t)b * HD * CTX;

    // Q fragments (A-operand), rows q0..q0+15
    bf16x8 qf[4];
#pragma unroll
    for (int ks = 0; ks < 4; ks++)
        qf[ks] = *(const bf16x8*)(qb + (q0 + lo) * HD + ks * 32 + hi * 8);

    fx4 o[8];
#pragma unroll
    for (int h = 0; h < 8; h++) o[h] = fx4{0.f, 0.f, 0.f, 0.f};
    float m[4], l[4];
#pragma unroll
    for (int j = 0; j < 4; j++) { m[j] = -INFINITY; l[j] = 0.f; }

    const int nkv = (q0 + 15) / 64 + 1;
    for (int it = 0; it < nkv; it++) {
        const int kv0 = it * 64;
        // ---- S = Q K^T (rows=q, cols=kv) ----
        fx4 s[4];
#pragma unroll
        for (int n = 0; n < 4; n++) s[n] = fx4{0.f, 0.f, 0.f, 0.f};
#pragma unroll
        for (int n = 0; n < 4; n++) {
#pragma unroll
            for (int ks = 0; ks < 4; ks++) {
                bf16x8 kf = *(const bf16x8*)(kb + (kv0 + n * 16 + lo) * HD + ks * 32 + hi * 8);
                s[n] = __builtin_amdgcn_mfma_f32_16x16x32_bf16(qf[ks], kf, s[n], 0, 0, 0);
            }
        }
        const bool diag = (kv0 + 64 > q0);
        // ---- online softmax (per row j, reduce across the 16 lanes lo=0..15) ----
#pragma unroll
        for (int j = 0; j < 4; j++) {
            const int r = q0 + hi * 4 + j;
            float mx = -INFINITY;
#pragma unroll
            for (int n = 0; n < 4; n++) {
                if (diag && (kv0 + n * 16 + lo) > r) s[n][j] = -INFINITY;
                mx = fmaxf(mx, s[n][j]);
            }
            mx = fmaxf(mx, __shfl_xor(mx, 1));
            mx = fmaxf(mx, __shfl_xor(mx, 2));
            mx = fmaxf(mx, __shfl_xor(mx, 4));
            mx = fmaxf(mx, __shfl_xor(mx, 8));
            const float mn = fmaxf(m[j], mx);
            const float f  = __expf(m[j] - mn);
            m[j] = mn;
            float sum = 0.f;
#pragma unroll
            for (int n = 0; n < 4; n++) {
                const float p = __expf(s[n][j] - mn);
                s[n][j] = p;
                sum += p;
            }
            sum += __shfl_xor(sum, 1);
            sum += __shfl_xor(sum, 2);
            sum += __shfl_xor(sum, 4);
            sum += __shfl_xor(sum, 8);
            l[j] = l[j] * f + sum;
#pragma unroll
            for (int h = 0; h < 8; h++) o[h][j] *= f;
#pragma unroll
            for (int n = 0; n < 4; n++)
                p_lds[wave][hi * 4 + j][n * 16 + lo] = f2bf(s[n][j]);
        }
        asm volatile("" ::: "memory");   // order LDS write -> read (same wave)
        // ---- PV: A = P (16 x 64), B = V (64 x 128) via Vt ----
        bf16x8 pa[2];
#pragma unroll
        for (int kk = 0; kk < 2; kk++)
            pa[kk] = *(const bf16x8*)(&p_lds[wave][lo][kk * 32 + hi * 8]);
#pragma unroll
        for (int h = 0; h < 8; h++) {
#pragma unroll
            for (int kk = 0; kk < 2; kk++) {
                bf16x8 vf = *(const bf16x8*)(vb + (h * 16 + lo) * CTX + kv0 + kk * 32 + hi * 8);
                o[h] = __builtin_amdgcn_mfma_f32_16x16x32_bf16(pa[kk], vf, o[h], 0, 0, 0);
            }
        }
    }

    // ---- epilogue: out fp32 [B][C][H] ----
    float* ob = out + (size_t)b * CTX * HD;
#pragma unroll
    for (int j = 0; j < 4; j++) {
        const float inv = 1.0f / l[j];
        const int r = q0 + hi * 4 + j;
#pragma unroll
        for (int h = 0; h < 8; h++)
            ob[r * HD + h * 16 + lo] = o[h][j] * inv;
    }
}

extern "C" void kernel_launch(void* const* d_in, const int* in_sizes, int n_in,
                              void* d_out, int out_size, void* d_ws, size_t ws_size,
                              hipStream_t stream) {
    const float* x  = (const float*)d_in[0];
    const float* Wq = (const float*)d_in[1];
    const float* Wk = (const float*)d_in[2];
    const float* Wv = (const float*)d_in[3];

    // workspace layout (bf16): Wt[3][H][E] | q[B*C][H] | k[B*C][H] | Vt[B][H][C]
    ushort* Wt = (ushort*)d_ws;                                  // 786 KB
    ushort* qw = (ushort*)((char*)d_ws + (1 << 20));             // 4 MB
    ushort* kw = qw + (size_t)BATCH * CTX * HD;                  // 4 MB
    ushort* vw = kw + (size_t)BATCH * CTX * HD;                  // 4 MB

    wt_kernel<<<(3 * HD * EMB) / 256, 256, 0, stream>>>(Wq, Wk, Wv, Wt);
    proj_kernel<<<(BATCH * CTX) / 64, 256, 0, stream>>>(x, Wt, qw, kw, vw);
    attn_kernel<<<dim3(CTX / 32, BATCH), 128, 0, stream>>>(qw, kw, vw, (float*)d_out);
}

// Round 2
// 202.426 us; speedup vs baseline: 1.7848x; 1.7848x over previous
//
#include <hip/hip_runtime.h>
#include <hip/hip_bf16.h>

#define BATCH 8
#define CTX   2048
#define EMB   1024
#define HD    128

using bf16x8 = __attribute__((ext_vector_type(8))) short;
using fx4    = __attribute__((ext_vector_type(4))) float;

__device__ __forceinline__ ushort f2bf(float f) {
    union { float f; unsigned u; } v; v.f = f;
    unsigned u = v.u;
    u += 0x7fffu + ((u >> 16) & 1u);   // RNE
    return (ushort)(u >> 16);
}

__device__ __forceinline__ unsigned cvtpk(float a, float b) {
    unsigned r;
    asm("v_cvt_pk_bf16_f32 %0, %1, %2" : "=v"(r) : "v"(a), "v"(b));
    return r;
}

__device__ __forceinline__ void gload16(const void* g, void* l) {
    __builtin_amdgcn_global_load_lds(
        (const __attribute__((address_space(1))) unsigned*)g,
        (__attribute__((address_space(3))) unsigned*)l, 16, 0, 0);
}

// ---------------- kernel 1: W (E,H) fp32 -> Wt (3,H,E) bf16 ----------------
__global__ void wt_kernel(const float* __restrict__ Wq, const float* __restrict__ Wk,
                          const float* __restrict__ Wv, ushort* __restrict__ Wt) {
    int idx = blockIdx.x * blockDim.x + threadIdx.x;      // [3][HD][EMB]
    int e = idx % EMB;
    int h = (idx / EMB) % HD;
    int w = idx / (EMB * HD);
    const float* W = (w == 0) ? Wq : (w == 1) ? Wk : Wv;
    Wt[idx] = f2bf(W[e * HD + h]);
}

// ---------------- kernel 2: tiled projection GEMM ---------------------------
// C[M=16384][N=384] = x[M][K=1024] * W[K][N]; Wt = W^T bf16 [N][K].
// BM=128, BN=128 (= one of q/k/v per column tile), BK=64, 4 waves.
// A staged fp32 (converted at read via v_cvt_pk_bf16_f32), B staged bf16.
// global_load_lds linear dest + XOR-pre-swizzled global source; reads apply
// the same XOR -> conflict-free ds_read_b128.
__global__ __launch_bounds__(256) void proj_kernel(
        const float* __restrict__ x, const ushort* __restrict__ Wt,
        ushort* __restrict__ q, ushort* __restrict__ k, ushort* __restrict__ vt) {
    __shared__ __align__(16) float  As[128 * 64];   // 32 KB
    __shared__ __align__(16) ushort Bs[128 * 64];   // 16 KB

    const int t    = threadIdx.x;
    const int wave = t >> 6;
    const int lane = t & 63;
    const int lo = lane & 15, hi = lane >> 4;
    const int wr = wave >> 1, wc = wave & 1;        // wave's 64x64 sub-tile
    const int bn   = blockIdx.x;                    // 0=q, 1=k, 2=v
    const int brow = blockIdx.y * 128;

    const char* Ab = (const char*)As;
    const char* Bb = (const char*)Bs;

    fx4 acc[4][4];
#pragma unroll
    for (int m2 = 0; m2 < 4; m2++)
#pragma unroll
        for (int n = 0; n < 4; n++) acc[m2][n] = fx4{0.f, 0.f, 0.f, 0.f};

    // staging geometry (16B chunks). A: 256B rows, 16 slots; B: 128B rows, 8 slots.
    const int arow_s = t >> 4;                              // + r*16
    const int acol_s = ((t & 15) ^ ((t >> 4) & 7)) << 2;    // f32 elems (src pre-swizzle)
    const int brow_s = t >> 3;                              // + r*32
    const int bcol_s = ((t & 7) ^ ((t >> 3) & 7)) << 3;     // bf16 elems
    const int ldsbase = wave * 1024;                        // wave-uniform, bytes

    for (int k0 = 0; k0 < EMB; k0 += 64) {
#pragma unroll
        for (int r = 0; r < 8; r++)
            gload16(x + (size_t)(brow + r * 16 + arow_s) * EMB + k0 + acol_s,
                    (char*)As + r * 4096 + ldsbase);
#pragma unroll
        for (int r = 0; r < 4; r++)
            gload16(Wt + (size_t)(bn * 128 + r * 32 + brow_s) * EMB + k0 + bcol_s,
                    (char*)Bs + r * 4096 + ldsbase);
        __syncthreads();

#pragma unroll
        for (int ks = 0; ks < 2; ks++) {
            bf16x8 af[4], bfr[4];
#pragma unroll
            for (int m2 = 0; m2 < 4; m2++) {
                const int rowA = wr * 64 + m2 * 16 + lo;
                const unsigned sw = (rowA & 7) << 4;
                const unsigned ub = rowA * 256 + ks * 128 + hi * 32;
                fx4 a0 = *(const fx4*)(Ab + (ub ^ sw));
                fx4 a1 = *(const fx4*)(Ab + ((ub + 16) ^ sw));
                union { unsigned u[4]; bf16x8 v; } pk;
                pk.u[0] = cvtpk(a0[0], a0[1]);
                pk.u[1] = cvtpk(a0[2], a0[3]);
                pk.u[2] = cvtpk(a1[0], a1[1]);
                pk.u[3] = cvtpk(a1[2], a1[3]);
                af[m2] = pk.v;
            }
#pragma unroll
            for (int n = 0; n < 4; n++) {
                const int rowB = wc * 64 + n * 16 + lo;
                const unsigned ub = rowB * 128 + ks * 64 + hi * 16;
                bfr[n] = *(const bf16x8*)(Bb + (ub ^ ((rowB & 7) << 4)));
            }
#pragma unroll
            for (int m2 = 0; m2 < 4; m2++)
#pragma unroll
                for (int n = 0; n < 4; n++)
                    acc[m2][n] = __builtin_amdgcn_mfma_f32_16x16x32_bf16(af[m2], bfr[n], acc[m2][n], 0, 0, 0);
        }
        __syncthreads();
    }

    // epilogue: D layout col = lane&15, row = (lane>>4)*4 + j
    const float qscale = 0.03125f;   // 1/sqrt(1024)
#pragma unroll
    for (int m2 = 0; m2 < 4; m2++) {
#pragma unroll
        for (int n = 0; n < 4; n++) {
            const int c = wc * 64 + n * 16 + lo;
#pragma unroll
            for (int j = 0; j < 4; j++) {
                const int r = brow + wr * 64 + m2 * 16 + hi * 4 + j;
                if (bn == 0)      q[(size_t)r * HD + c] = f2bf(acc[m2][n][j] * qscale);
                else if (bn == 1) k[(size_t)r * HD + c] = f2bf(acc[m2][n][j]);
                else {
                    const int bb = r >> 11, cc = r & (CTX - 1);
                    vt[((size_t)bb * HD + c) * CTX + cc] = f2bf(acc[m2][n][j]);
                }
            }
        }
    }
}

// ---------------- kernel 3: causal flash attention (KV-split) ---------------
// grid = (C/32, B), 256 thr (4 waves). wq = q sub-group (16 rows), wk = KV
// half: wave handles tiles it = wk, wk+2, ... Partials merged through LDS.
__global__ __launch_bounds__(256) void attn_kernel(
        const ushort* __restrict__ q, const ushort* __restrict__ k,
        const ushort* __restrict__ vt, float* __restrict__ out) {
    __shared__ __align__(16) char p_lds[4][2048];       // P tile, XOR-swizzled
    __shared__ float om_lds[2][16][129];                // partner O partial
    __shared__ float ml_lds[2][2][16];                  // partner m / l

    const int b    = blockIdx.y;
    const int qt   = gridDim.x - 1 - blockIdx.x;   // longest tiles first
    const int wave = threadIdx.x >> 6;
    const int lane = threadIdx.x & 63;
    const int lo = lane & 15, hi = lane >> 4;
    const int wq = wave & 1, wk = wave >> 1;
    const int q0 = qt * 32 + wq * 16;

    const ushort* qb = q  + (size_t)b * CTX * HD;
    const ushort* kb = k  + (size_t)b * CTX * HD;
    const ushort* vb = vt + (size_t)b * HD * CTX;

    bf16x8 qf[4];
#pragma unroll
    for (int ks = 0; ks < 4; ks++)
        qf[ks] = *(const bf16x8*)(qb + (q0 + lo) * HD + ks * 32 + hi * 8);

    fx4 o[8];
#pragma unroll
    for (int h = 0; h < 8; h++) o[h] = fx4{0.f, 0.f, 0.f, 0.f};
    float m[4], l[4];
#pragma unroll
    for (int j = 0; j < 4; j++) { m[j] = -INFINITY; l[j] = 0.f; }

    const int nkv = (q0 + 15) / 64 + 1;
    for (int it = wk; it < nkv; it += 2) {
        const int kv0 = it * 64;
        // ---- S = Q K^T ----
        fx4 s[4];
#pragma unroll
        for (int n = 0; n < 4; n++) s[n] = fx4{0.f, 0.f, 0.f, 0.f};
#pragma unroll
        for (int n = 0; n < 4; n++) {
#pragma unroll
            for (int ks = 0; ks < 4; ks++) {
                bf16x8 kf = *(const bf16x8*)(kb + (kv0 + n * 16 + lo) * HD + ks * 32 + hi * 8);
                s[n] = __builtin_amdgcn_mfma_f32_16x16x32_bf16(qf[ks], kf, s[n], 0, 0, 0);
            }
        }
        // ---- V prefetch (independent of softmax) ----
        bf16x8 vf[8][2];
#pragma unroll
        for (int h = 0; h < 8; h++)
#pragma unroll
            for (int kk = 0; kk < 2; kk++)
                vf[h][kk] = *(const bf16x8*)(vb + (h * 16 + lo) * CTX + kv0 + kk * 32 + hi * 8);

        const bool diag = (kv0 + 64 > q0);
        // ---- online softmax ----
#pragma unroll
        for (int j = 0; j < 4; j++) {
            const int r = q0 + hi * 4 + j;
            float mx = -INFINITY;
#pragma unroll
            for (int n = 0; n < 4; n++) {
                if (diag && (kv0 + n * 16 + lo) > r) s[n][j] = -INFINITY;
                mx = fmaxf(mx, s[n][j]);
            }
            mx = fmaxf(mx, __shfl_xor(mx, 1));
            mx = fmaxf(mx, __shfl_xor(mx, 2));
            mx = fmaxf(mx, __shfl_xor(mx, 4));
            mx = fmaxf(mx, __shfl_xor(mx, 8));
            const float mn = fmaxf(m[j], mx);
            const float f  = __expf(m[j] - mn);
            m[j] = mn;
            float sum = 0.f;
#pragma unroll
            for (int n = 0; n < 4; n++) {
                const float p = __expf(s[n][j] - mn);
                s[n][j] = p;
                sum += p;
            }
            sum += __shfl_xor(sum, 1);
            sum += __shfl_xor(sum, 2);
            sum += __shfl_xor(sum, 4);
            sum += __shfl_xor(sum, 8);
            l[j] = l[j] * f + sum;
#pragma unroll
            for (int h = 0; h < 8; h++) o[h][j] *= f;
            const int row = hi * 4 + j;
            const unsigned sw = (row & 7) << 4;
#pragma unroll
            for (int n = 0; n < 4; n++) {
                const unsigned cb = (unsigned)((n * 16 + lo) * 2);
                *(ushort*)(p_lds[wave] + row * 128 + (cb ^ sw)) = f2bf(s[n][j]);
            }
        }
        asm volatile("" ::: "memory");
        // ---- PV ----
        bf16x8 pa[2];
#pragma unroll
        for (int kk = 0; kk < 2; kk++) {
            const unsigned ub = (unsigned)(kk * 64 + hi * 16);
            pa[kk] = *(const bf16x8*)(p_lds[wave] + lo * 128 + (ub ^ ((lo & 7) << 4)));
        }
#pragma unroll
        for (int h = 0; h < 8; h++)
#pragma unroll
            for (int kk = 0; kk < 2; kk++)
                o[h] = __builtin_amdgcn_mfma_f32_16x16x32_bf16(pa[kk], vf[h][kk], o[h], 0, 0, 0);
    }

    // ---- merge the two KV halves + write out ----
    if (wk == 1) {
#pragma unroll
        for (int j = 0; j < 4; j++) {
            const int row = hi * 4 + j;
            if (lo == 0) { ml_lds[wq][0][row] = m[j]; ml_lds[wq][1][row] = l[j]; }
#pragma unroll
            for (int h = 0; h < 8; h++) om_lds[wq][row][h * 16 + lo] = o[h][j];
        }
    }
    __syncthreads();
    if (wk == 0) {
        float* ob = out + ((size_t)b * CTX + q0) * HD;
#pragma unroll
        for (int j = 0; j < 4; j++) {
            const int row = hi * 4 + j;
            const float mB = ml_lds[wq][0][row], lB = ml_lds[wq][1][row];
            const float mt = fmaxf(m[j], mB);
            const float fA = __expf(m[j] - mt);
            const float fB = __expf(mB - mt);
            const float inv = 1.0f / (l[j] * fA + lB * fB);
#pragma unroll
            for (int h = 0; h < 8; h++)
                ob[row * HD + h * 16 + lo] =
                    (o[h][j] * fA + om_lds[wq][row][h * 16 + lo] * fB) * inv;
        }
    }
}

extern "C" void kernel_launch(void* const* d_in, const int* in_sizes, int n_in,
                              void* d_out, int out_size, void* d_ws, size_t ws_size,
                              hipStream_t stream) {
    const float* x  = (const float*)d_in[0];
    const float* Wq = (const float*)d_in[1];
    const float* Wk = (const float*)d_in[2];
    const float* Wv = (const float*)d_in[3];

    // ws: Wt[3][H][E] bf16 (768KB, pad to 1MB) | q[B*C][H] | k[B*C][H] | Vt[B][H][C]
    ushort* Wt = (ushort*)d_ws;
    ushort* qw = (ushort*)((char*)d_ws + (1 << 20));
    ushort* kw = qw + (size_t)BATCH * CTX * HD;
    ushort* vw = kw + (size_t)BATCH * CTX * HD;

    wt_kernel<<<(3 * HD * EMB) / 256, 256, 0, stream>>>(Wq, Wk, Wv, Wt);
    proj_kernel<<<dim3(3, 128), 256, 0, stream>>>(x, Wt, qw, kw, vw);
    attn_kernel<<<dim3(CTX / 32, BATCH), 256, 0, stream>>>(qw, kw, vw, (float*)d_out);
}

// Round 3
// 179.914 us; speedup vs baseline: 2.0081x; 1.1251x over previous
//
#include <hip/hip_runtime.h>
#include <hip/hip_bf16.h>

#define BATCH 8
#define CTX   2048
#define EMB   1024
#define HD    128

using bf16x8 = __attribute__((ext_vector_type(8))) short;
using fx4    = __attribute__((ext_vector_type(4))) float;

__device__ __forceinline__ ushort f2bf(float f) {
    union { float f; unsigned u; } v; v.f = f;
    unsigned u = v.u;
    u += 0x7fffu + ((u >> 16) & 1u);   // RNE
    return (ushort)(u >> 16);
}

__device__ __forceinline__ unsigned cvtpk(float a, float b) {
    unsigned r;
    asm("v_cvt_pk_bf16_f32 %0, %1, %2" : "=v"(r) : "v"(a), "v"(b));
    return r;
}

__device__ __forceinline__ void gload16(const void* g, void* l) {
    __builtin_amdgcn_global_load_lds(
        (const __attribute__((address_space(1))) unsigned*)g,
        (__attribute__((address_space(3))) unsigned*)l, 16, 0, 0);
}

// ---------------- kernel 1: W (E,H) fp32 -> Wt (3,H,E) bf16 ----------------
__global__ void wt_kernel(const float* __restrict__ Wq, const float* __restrict__ Wk,
                          const float* __restrict__ Wv, ushort* __restrict__ Wt) {
    int idx = blockIdx.x * blockDim.x + threadIdx.x;      // [3][HD][EMB]
    int e = idx % EMB;
    int h = (idx / EMB) % HD;
    int w = idx / (EMB * HD);
    const float* W = (w == 0) ? Wq : (w == 1) ? Wk : Wv;
    Wt[idx] = f2bf(W[e * HD + h]);
}

// ---------------- kernel 2: tiled projection GEMM ---------------------------
__global__ __launch_bounds__(256) void proj_kernel(
        const float* __restrict__ x, const ushort* __restrict__ Wt,
        ushort* __restrict__ q, ushort* __restrict__ k, ushort* __restrict__ vt) {
    __shared__ __align__(16) float  As[128 * 64];   // 32 KB
    __shared__ __align__(16) ushort Bs[128 * 64];   // 16 KB

    const int t    = threadIdx.x;
    const int wave = t >> 6;
    const int lane = t & 63;
    const int lo = lane & 15, hi = lane >> 4;
    const int wr = wave >> 1, wc = wave & 1;
    const int bn   = blockIdx.x;                    // 0=q, 1=k, 2=v
    const int brow = blockIdx.y * 128;

    const char* Ab = (const char*)As;
    const char* Bb = (const char*)Bs;

    fx4 acc[4][4];
#pragma unroll
    for (int m2 = 0; m2 < 4; m2++)
#pragma unroll
        for (int n = 0; n < 4; n++) acc[m2][n] = fx4{0.f, 0.f, 0.f, 0.f};

    const int arow_s = t >> 4;
    const int acol_s = ((t & 15) ^ ((t >> 4) & 7)) << 2;
    const int brow_s = t >> 3;
    const int bcol_s = ((t & 7) ^ ((t >> 3) & 7)) << 3;
    const int ldsbase = wave * 1024;

    for (int k0 = 0; k0 < EMB; k0 += 64) {
#pragma unroll
        for (int r = 0; r < 8; r++)
            gload16(x + (size_t)(brow + r * 16 + arow_s) * EMB + k0 + acol_s,
                    (char*)As + r * 4096 + ldsbase);
#pragma unroll
        for (int r = 0; r < 4; r++)
            gload16(Wt + (size_t)(bn * 128 + r * 32 + brow_s) * EMB + k0 + bcol_s,
                    (char*)Bs + r * 4096 + ldsbase);
        __syncthreads();

#pragma unroll
        for (int ks = 0; ks < 2; ks++) {
            bf16x8 af[4], bfr[4];
#pragma unroll
            for (int m2 = 0; m2 < 4; m2++) {
                const int rowA = wr * 64 + m2 * 16 + lo;
                const unsigned sw = (rowA & 7) << 4;
                const unsigned ub = rowA * 256 + ks * 128 + hi * 32;
                fx4 a0 = *(const fx4*)(Ab + (ub ^ sw));
                fx4 a1 = *(const fx4*)(Ab + ((ub + 16) ^ sw));
                union { unsigned u[4]; bf16x8 v; } pk;
                pk.u[0] = cvtpk(a0[0], a0[1]);
                pk.u[1] = cvtpk(a0[2], a0[3]);
                pk.u[2] = cvtpk(a1[0], a1[1]);
                pk.u[3] = cvtpk(a1[2], a1[3]);
                af[m2] = pk.v;
            }
#pragma unroll
            for (int n = 0; n < 4; n++) {
                const int rowB = wc * 64 + n * 16 + lo;
                const unsigned ub = rowB * 128 + ks * 64 + hi * 16;
                bfr[n] = *(const bf16x8*)(Bb + (ub ^ ((rowB & 7) << 4)));
            }
#pragma unroll
            for (int m2 = 0; m2 < 4; m2++)
#pragma unroll
                for (int n = 0; n < 4; n++)
                    acc[m2][n] = __builtin_amdgcn_mfma_f32_16x16x32_bf16(af[m2], bfr[n], acc[m2][n], 0, 0, 0);
        }
        __syncthreads();
    }

    const float qscale = 0.03125f;   // 1/sqrt(1024)
#pragma unroll
    for (int m2 = 0; m2 < 4; m2++) {
#pragma unroll
        for (int n = 0; n < 4; n++) {
            const int c = wc * 64 + n * 16 + lo;
#pragma unroll
            for (int j = 0; j < 4; j++) {
                const int r = brow + wr * 64 + m2 * 16 + hi * 4 + j;
                if (bn == 0)      q[(size_t)r * HD + c] = f2bf(acc[m2][n][j] * qscale);
                else if (bn == 1) k[(size_t)r * HD + c] = f2bf(acc[m2][n][j]);
                else {
                    const int bb = r >> 11, cc = r & (CTX - 1);
                    vt[((size_t)bb * HD + c) * CTX + cc] = f2bf(acc[m2][n][j]);
                }
            }
        }
    }
}

// ---------------- kernel 3: causal flash attention (KV-split) ---------------
// Defer-max softmax (T13 aggressive): m init 0, THR=16; fast path has NO
// cross-lane ops and NO O-rescale. Lane-local l partials, reduced once after
// the KV loop. Rare-overflow fallback = full reduce + rescale (correct always).
__global__ __launch_bounds__(256) void attn_kernel(
        const ushort* __restrict__ q, const ushort* __restrict__ k,
        const ushort* __restrict__ vt, float* __restrict__ out) {
    __shared__ __align__(16) char p_lds[4][2048];       // P tile, XOR-swizzled
    __shared__ float om_lds[2][16][129];                // partner O partial
    __shared__ float ml_lds[2][2][16];                  // partner m / l

    const int b    = blockIdx.y;
    const int qt   = gridDim.x - 1 - blockIdx.x;   // longest tiles first
    const int wave = threadIdx.x >> 6;
    const int lane = threadIdx.x & 63;
    const int lo = lane & 15, hi = lane >> 4;
    const int wq = wave & 1, wk = wave >> 1;
    const int q0 = qt * 32 + wq * 16;

    const ushort* qb = q  + (size_t)b * CTX * HD;
    const ushort* kb = k  + (size_t)b * CTX * HD;
    const ushort* vb = vt + (size_t)b * HD * CTX;

    bf16x8 qf[4];
#pragma unroll
    for (int ks = 0; ks < 4; ks++)
        qf[ks] = *(const bf16x8*)(qb + (q0 + lo) * HD + ks * 32 + hi * 8);

    fx4 o[8];
#pragma unroll
    for (int h = 0; h < 8; h++) o[h] = fx4{0.f, 0.f, 0.f, 0.f};
    float m[4], l[4];
#pragma unroll
    for (int j = 0; j < 4; j++) { m[j] = 0.f; l[j] = 0.f; }

    const int nkv = (q0 + 15) / 64 + 1;
    for (int it = wk; it < nkv; it += 2) {
        const int kv0 = it * 64;
        // ---- V prefetch first: fully independent, max overlap ----
        bf16x8 vf[8][2];
#pragma unroll
        for (int h = 0; h < 8; h++)
#pragma unroll
            for (int kk = 0; kk < 2; kk++)
                vf[h][kk] = *(const bf16x8*)(vb + (h * 16 + lo) * CTX + kv0 + kk * 32 + hi * 8);

        // ---- S = Q K^T ----
        fx4 s[4];
#pragma unroll
        for (int n = 0; n < 4; n++) s[n] = fx4{0.f, 0.f, 0.f, 0.f};
        __builtin_amdgcn_s_setprio(1);
#pragma unroll
        for (int n = 0; n < 4; n++) {
#pragma unroll
            for (int ks = 0; ks < 4; ks++) {
                bf16x8 kf = *(const bf16x8*)(kb + (kv0 + n * 16 + lo) * HD + ks * 32 + hi * 8);
                s[n] = __builtin_amdgcn_mfma_f32_16x16x32_bf16(qf[ks], kf, s[n], 0, 0, 0);
            }
        }
        __builtin_amdgcn_s_setprio(0);

        const bool diag = (kv0 + 64 > q0);
        // ---- mask + overflow check (lane-local, no cross-lane) ----
        float pmax[4];
        int allok = 1;
#pragma unroll
        for (int j = 0; j < 4; j++) {
            const int r = q0 + hi * 4 + j;
            if (diag) {
#pragma unroll
                for (int n = 0; n < 4; n++)
                    if ((kv0 + n * 16 + lo) > r) s[n][j] = -INFINITY;
            }
            pmax[j] = fmaxf(fmaxf(s[0][j], s[1][j]), fmaxf(s[2][j], s[3][j]));
            allok &= (pmax[j] <= m[j] + 16.0f);
        }
        if (!__all(allok)) {
            // slow path (rare): full cross-lane max + rescale
#pragma unroll
            for (int j = 0; j < 4; j++) {
                float mx = pmax[j];
                mx = fmaxf(mx, __shfl_xor(mx, 1));
                mx = fmaxf(mx, __shfl_xor(mx, 2));
                mx = fmaxf(mx, __shfl_xor(mx, 4));
                mx = fmaxf(mx, __shfl_xor(mx, 8));
                const float mn = fmaxf(m[j], mx);
                const float f  = __expf(m[j] - mn);
                l[j] *= f;
#pragma unroll
                for (int h = 0; h < 8; h++) o[h][j] *= f;
                m[j] = mn;
            }
        }
        // ---- fast exp + lane-local l accumulation + P pack ----
#pragma unroll
        for (int j = 0; j < 4; j++) {
            float sum = 0.f;
#pragma unroll
            for (int n = 0; n < 4; n++) {
                const float p = __expf(s[n][j] - m[j]);
                s[n][j] = p;
                sum += p;
            }
            l[j] += sum;
            const int row = hi * 4 + j;
            const unsigned sw = (row & 7) << 4;
#pragma unroll
            for (int n = 0; n < 4; n++) {
                const unsigned cb = (unsigned)((n * 16 + lo) * 2);
                *(ushort*)(p_lds[wave] + row * 128 + (cb ^ sw)) = f2bf(s[n][j]);
            }
        }
        asm volatile("" ::: "memory");
        // ---- PV ----
        bf16x8 pa[2];
#pragma unroll
        for (int kk = 0; kk < 2; kk++) {
            const unsigned ub = (unsigned)(kk * 64 + hi * 16);
            pa[kk] = *(const bf16x8*)(p_lds[wave] + lo * 128 + (ub ^ ((lo & 7) << 4)));
        }
        __builtin_amdgcn_s_setprio(1);
#pragma unroll
        for (int h = 0; h < 8; h++)
#pragma unroll
            for (int kk = 0; kk < 2; kk++)
                o[h] = __builtin_amdgcn_mfma_f32_16x16x32_bf16(pa[kk], vf[h][kk], o[h], 0, 0, 0);
        __builtin_amdgcn_s_setprio(0);
    }

    // ---- one-time cross-lane l reduce (over the 16 lo lanes) ----
#pragma unroll
    for (int j = 0; j < 4; j++) {
        l[j] += __shfl_xor(l[j], 1);
        l[j] += __shfl_xor(l[j], 2);
        l[j] += __shfl_xor(l[j], 4);
        l[j] += __shfl_xor(l[j], 8);
    }

    // ---- merge the two KV halves + write out ----
    if (wk == 1) {
#pragma unroll
        for (int j = 0; j < 4; j++) {
            const int row = hi * 4 + j;
            if (lo == 0) { ml_lds[wq][0][row] = m[j]; ml_lds[wq][1][row] = l[j]; }
#pragma unroll
            for (int h = 0; h < 8; h++) om_lds[wq][row][h * 16 + lo] = o[h][j];
        }
    }
    __syncthreads();
    if (wk == 0) {
        float* ob = out + ((size_t)b * CTX + q0) * HD;
#pragma unroll
        for (int j = 0; j < 4; j++) {
            const int row = hi * 4 + j;
            const float mB = ml_lds[wq][0][row], lB = ml_lds[wq][1][row];
            const float mt = fmaxf(m[j], mB);
            const float fA = __expf(m[j] - mt);
            const float fB = __expf(mB - mt);
            const float inv = 1.0f / (l[j] * fA + lB * fB);
#pragma unroll
            for (int h = 0; h < 8; h++)
                ob[row * HD + h * 16 + lo] =
                    (o[h][j] * fA + om_lds[wq][row][h * 16 + lo] * fB) * inv;
        }
    }
}

extern "C" void kernel_launch(void* const* d_in, const int* in_sizes, int n_in,
                              void* d_out, int out_size, void* d_ws, size_t ws_size,
                              hipStream_t stream) {
    const float* x  = (const float*)d_in[0];
    const float* Wq = (const float*)d_in[1];
    const float* Wk = (const float*)d_in[2];
    const float* Wv = (const float*)d_in[3];

    ushort* Wt = (ushort*)d_ws;
    ushort* qw = (ushort*)((char*)d_ws + (1 << 20));
    ushort* kw = qw + (size_t)BATCH * CTX * HD;
    ushort* vw = kw + (size_t)BATCH * CTX * HD;

    wt_kernel<<<(3 * HD * EMB) / 256, 256, 0, stream>>>(Wq, Wk, Wv, Wt);
    proj_kernel<<<dim3(3, 128), 256, 0, stream>>>(x, Wt, qw, kw, vw);
    attn_kernel<<<dim3(CTX / 32, BATCH), 256, 0, stream>>>(qw, kw, vw, (float*)d_out);
}